// Round 6
// baseline (993.967 us; speedup 1.0000x reference)
//
#include <hip/hip_runtime.h>
#include <math.h>

#define HID 128
#define NUM_G 20
#define EF 4
#define NN 20000
#define NE 640000
#define K1 288            // 280 padded to 9*32
#define KN1 256           // node GEMM1 K
#define TS 136            // LDS stride (bf16): 272B rows -> 2-way conflict only (free)

typedef __attribute__((ext_vector_type(8))) short short8;
typedef __attribute__((ext_vector_type(4))) short short4v;
typedef __attribute__((ext_vector_type(4))) float floatx4;

// fast activations: approx rcp (v_rcp_f32) is fine at 0.1 abs tolerance
__device__ __forceinline__ float silu_f(float v){
    return v * __builtin_amdgcn_rcpf(1.0f + __expf(-v));
}
__device__ __forceinline__ float sigm_f(float v){
    return __builtin_amdgcn_rcpf(1.0f + __expf(-v));
}
__device__ __forceinline__ float tanh_f(float v){
    return 1.0f - 2.0f * __builtin_amdgcn_rcpf(1.0f + __expf(2.0f * v));
}
__device__ __forceinline__ unsigned short f2bf(float v){
    unsigned int u = __float_as_uint(v);
    u = (u + 0x7fffu + ((u >> 16) & 1u)) >> 16;
    return (unsigned short)u;
}
__device__ __forceinline__ float bf2f(unsigned int u){
    return __uint_as_float(u << 16);
}

__global__ __launch_bounds__(256) void prep_h_kernel(
    const float* __restrict__ h, unsigned short* __restrict__ h_bf)
{
    int i = (blockIdx.x * 256 + threadIdx.x) * 4;
    float4 v = *(const float4*)(h + i);
    short4v o;
    o[0] = (short)f2bf(v.x); o[1] = (short)f2bf(v.y);
    o[2] = (short)f2bf(v.z); o[3] = (short)f2bf(v.w);
    *(short4v*)(h_bf + i) = o;
}

__global__ __launch_bounds__(320) void prep_w_kernel(
    const float* __restrict__ W_e1, const float* __restrict__ W_e2,
    const float* __restrict__ W_x1, const float* __restrict__ W_n1,
    const float* __restrict__ W_n2,
    unsigned short* __restrict__ WT_e1, unsigned short* __restrict__ WT_e2,
    unsigned short* __restrict__ WT_x1, unsigned short* __restrict__ WT_n1,
    unsigned short* __restrict__ WT_n2)
{
    int n = blockIdx.x;
    int t = threadIdx.x;
    if (t < K1)  WT_e1[n*K1  + t] = (t < 280) ? f2bf(W_e1[t*HID + n]) : (unsigned short)0;
    if (t < KN1) WT_n1[n*KN1 + t] = f2bf(W_n1[t*HID + n]);
    if (t < HID) {
        WT_e2[n*HID + t] = f2bf(W_e2[t*HID + n]);
        WT_x1[n*HID + t] = f2bf(W_x1[t*HID + n]);
        WT_n2[n*HID + t] = f2bf(W_n2[t*HID + n]);
    }
}

// ---- counting sort of edges by dst ----
__global__ __launch_bounds__(256) void hist_kernel(
    const int* __restrict__ edge_index, int* __restrict__ counts)
{
    int e = blockIdx.x * 256 + threadIdx.x;
    atomicAdd(&counts[edge_index[NE + e]], 1);
}

__global__ __launch_bounds__(256) void scan_kernel(
    const int* __restrict__ counts, int* __restrict__ cursor)
{
    __shared__ int part[256];
    const int t = threadIdx.x;
    const int CH = (NN + 255) / 256;
    int base = t * CH;
    int s = 0;
    for (int i = 0; i < CH; ++i) { int idx = base + i; if (idx < NN) s += counts[idx]; }
    part[t] = s; __syncthreads();
    for (int off = 1; off < 256; off <<= 1) {
        int v = (t >= off) ? part[t - off] : 0;
        __syncthreads();
        part[t] += v;
        __syncthreads();
    }
    int run = (t == 0) ? 0 : part[t - 1];
    for (int i = 0; i < CH; ++i) {
        int idx = base + i;
        if (idx < NN) { cursor[idx] = run; run += counts[idx]; }
    }
}

__global__ __launch_bounds__(256) void scatter_kernel(
    const int* __restrict__ edge_index, int* __restrict__ cursor,
    int* __restrict__ order)
{
    int e = blockIdx.x * 256 + threadIdx.x;
    int d = edge_index[NE + e];
    int pos = atomicAdd(&cursor[d], 1);
    order[pos] = e;
}

// ---- edge kernel: ONE WAVE per block, 16 sorted edges, minimal LDS, atomics last ----
__global__ __launch_bounds__(64, 8) void egnn_edge_mfma(
    const float* __restrict__ x, const float* __restrict__ edge_attr,
    const int* __restrict__ edge_index, const int* __restrict__ order,
    const unsigned short* __restrict__ h_bf,
    const unsigned short* __restrict__ WT_e1,
    const unsigned short* __restrict__ WT_e2,
    const unsigned short* __restrict__ WT_x1,
    const float* __restrict__ b_e1, const float* __restrict__ b_e2,
    const float* __restrict__ W_g,  const float* __restrict__ b_g,
    const float* __restrict__ b_x1, const float* __restrict__ W_x2,
    float* __restrict__ agg, float* __restrict__ dxv)
{
    __shared__ __align__(16) unsigned short T[16*TS];   // m1, then m2
    __shared__ int   s_dst[17];                         // [16] = -1 sentinel
    __shared__ float s_g[16];
    __shared__ float s_vec[48];

    const int lane = threadIdx.x;
    const int quad = lane >> 4;
    const int l15  = lane & 15;
    const int e0   = blockIdx.x * 16;

    // --- meta in registers (lanes 0..15 own one edge each) ---
    int   ereg = 0, sreg = 0, dreg = 0;
    float rxr = 0.f, ryr = 0.f, rzr = 0.f, rreg = 0.f;
    if (lane < 16) {
        ereg = order[e0 + lane];
        sreg = edge_index[ereg];
        dreg = edge_index[NE + ereg];
        rxr = x[dreg*3+0] - x[sreg*3+0];
        ryr = x[dreg*3+1] - x[sreg*3+1];
        rzr = x[dreg*3+2] - x[sreg*3+2];
        rreg = sqrtf(rxr*rxr + ryr*ryr + rzr*rzr + 1e-8f);
        s_dst[lane] = dreg;
    }
    if (lane == 16) s_dst[16] = -1;

    // broadcast row-l15 meta to all quads
    const int   nd  = __shfl(dreg, l15);
    const int   ns  = __shfl(sreg, l15);
    const int   eid = __shfl(ereg, l15);
    const float rr  = __shfl(rreg, l15);

    // --- GEMM1 A-fragments: direct global gather + in-register RBF ---
    const unsigned short* hd = h_bf + (size_t)nd*HID + quad*8;
    const unsigned short* hs = h_bf + (size_t)ns*HID + quad*8;
    short8 a1[9];
    #pragma unroll
    for (int kc = 0; kc < 4; ++kc) a1[kc]   = *(const short8*)(hd + kc*32);
    #pragma unroll
    for (int kc = 0; kc < 4; ++kc) a1[4+kc] = *(const short8*)(hs + kc*32);
    {
        const float step  = 10.0f / 19.0f;
        const float coeff = -0.5f / (step*step);
        short8 v;
        #pragma unroll
        for (int j = 0; j < 8; ++j) {
            int col = quad*8 + j;     // 0..31 within the last K-chunk (256..287 overall)
            float val = 0.f;
            if (col < NUM_G) {
                float d = rr - step*(float)col;
                val = __expf(coeff*d*d);
            } else if (col < NUM_G+EF) {
                val = edge_attr[(size_t)eid*EF + (col-NUM_G)];
            }
            v[j] = (short)f2bf(val);
        }
        a1[8] = v;
    }

    floatx4 acc[8];
    #pragma unroll
    for (int t = 0; t < 8; ++t) acc[t] = (floatx4){0,0,0,0};
    #pragma unroll
    for (int kc = 0; kc < 9; ++kc) {
        #pragma unroll
        for (int t = 0; t < 8; ++t) {
            short8 b = *(const short8*)(WT_e1 + (size_t)(t*16+l15)*K1 + kc*32 + quad*8);
            acc[t] = __builtin_amdgcn_mfma_f32_16x16x32_bf16(a1[kc], b, acc[t], 0, 0, 0);
        }
    }
    // epilogue 1: m1 = silu(acc + b_e1) -> T
    #pragma unroll
    for (int t = 0; t < 8; ++t) {
        int col = t*16 + l15;
        float bv = b_e1[col];
        #pragma unroll
        for (int i = 0; i < 4; ++i)
            T[(quad*4+i)*TS + col] = f2bf(silu_f(acc[t][i] + bv));
    }
    __builtin_amdgcn_wave_barrier();

    // --- GEMM2: m2 = silu(m1 @ W_e2 + b), gate ---
    short8 a2[4];
    #pragma unroll
    for (int kc = 0; kc < 4; ++kc)
        a2[kc] = *(const short8*)(&T[l15*TS + kc*32 + quad*8]);
    #pragma unroll
    for (int t = 0; t < 8; ++t) acc[t] = (floatx4){0,0,0,0};
    #pragma unroll
    for (int kc = 0; kc < 4; ++kc) {
        #pragma unroll
        for (int t = 0; t < 8; ++t) {
            short8 b = *(const short8*)(WT_e2 + (size_t)(t*16+l15)*HID + kc*32 + quad*8);
            acc[t] = __builtin_amdgcn_mfma_f32_16x16x32_bf16(a2[kc], b, acc[t], 0, 0, 0);
        }
    }
    {
        float gp[4] = {0,0,0,0};
        #pragma unroll
        for (int t = 0; t < 8; ++t) {
            int col = t*16 + l15;
            float bv = b_e2[col];
            float wgv = W_g[col];
            #pragma unroll
            for (int i = 0; i < 4; ++i) {
                float m2 = silu_f(acc[t][i] + bv);
                gp[i] += m2 * wgv;
                T[(quad*4+i)*TS + col] = f2bf(m2);   // overwrite m1 with m2
            }
        }
        const float bg0 = b_g[0];
        #pragma unroll
        for (int i = 0; i < 4; ++i) {
            gp[i] += __shfl_xor(gp[i], 1);
            gp[i] += __shfl_xor(gp[i], 2);
            gp[i] += __shfl_xor(gp[i], 4);
            gp[i] += __shfl_xor(gp[i], 8);
        }
        if (l15 == 0) {
            #pragma unroll
            for (int i = 0; i < 4; ++i) s_g[quad*4 + i] = sigm_f(gp[i] + bg0);
        }
    }
    __builtin_amdgcn_wave_barrier();

    // --- GEMM3: coord head (before any atomics) ---
    short8 a3[4];
    #pragma unroll
    for (int kc = 0; kc < 4; ++kc)
        a3[kc] = *(const short8*)(&T[l15*TS + kc*32 + quad*8]);
    #pragma unroll
    for (int t = 0; t < 8; ++t) acc[t] = (floatx4){0,0,0,0};
    #pragma unroll
    for (int kc = 0; kc < 4; ++kc) {
        #pragma unroll
        for (int t = 0; t < 8; ++t) {
            short8 b = *(const short8*)(WT_x1 + (size_t)(t*16+l15)*HID + kc*32 + quad*8);
            acc[t] = __builtin_amdgcn_mfma_f32_16x16x32_bf16(a3[kc], b, acc[t], 0, 0, 0);
        }
    }
    {
        float cp[4] = {0,0,0,0};
        #pragma unroll
        for (int t = 0; t < 8; ++t) {
            int col = t*16 + l15;
            float bv = b_x1[col];
            float wx = W_x2[col];
            #pragma unroll
            for (int i = 0; i < 4; ++i)
                cp[i] += silu_f(acc[t][i] + bv) * wx;
        }
        #pragma unroll
        for (int i = 0; i < 4; ++i) {
            cp[i] += __shfl_xor(cp[i], 1);
            cp[i] += __shfl_xor(cp[i], 2);
            cp[i] += __shfl_xor(cp[i], 4);
            cp[i] += __shfl_xor(cp[i], 8);
        }
        if (l15 < 3) {
            #pragma unroll
            for (int i = 0; i < 4; ++i) {
                int row = quad*4 + i;
                float rxv = __shfl(rxr, row);
                float ryv = __shfl(ryr, row);
                float rzv = __shfl(rzr, row);
                float rv  = __shfl(rreg, row);
                float relc = (l15 == 0) ? rxv : ((l15 == 1) ? ryv : rzv);
                s_vec[row*3 + l15] = relc * __builtin_amdgcn_rcpf(rv + 1.0f) * tanh_f(cp[i]);
            }
        }
    }
    __builtin_amdgcn_wave_barrier();

    // --- ALL scatters at the very end (no later vmem waits behind atomics) ---
    {
        float am0 = 0.f, am1 = 0.f;
        #pragma unroll
        for (int r = 0; r < 16; ++r) {
            unsigned int pv = *(const unsigned int*)(&T[r*TS + lane*2]);
            float gr = s_g[r];
            am0 += bf2f(pv & 0xffffu) * gr;
            am1 += bf2f(pv >> 16) * gr;
            int dr = s_dst[r];
            if (dr != s_dst[r+1]) {
                atomicAdd(&agg[(size_t)dr*HID + lane*2],     am0);
                atomicAdd(&agg[(size_t)dr*HID + lane*2 + 1], am1);
                am0 = 0.f; am1 = 0.f;
            }
        }
    }
    if (lane < 3) {
        float a = 0.f;
        #pragma unroll
        for (int r = 0; r < 16; ++r) {
            a += s_vec[r*3 + lane];
            int dr = s_dst[r];
            if (dr != s_dst[r+1]) {
                atomicAdd(&dxv[(size_t)dr*3 + lane], a);
                a = 0.f;
            }
        }
    }
}

// ---- node kernel: ONE WAVE per block, 16 nodes ----
__global__ __launch_bounds__(64, 8) void egnn_node_mfma(
    const float* __restrict__ h, const float* __restrict__ x,
    const int* __restrict__ mask,
    const unsigned short* __restrict__ h_bf,
    const float* __restrict__ agg, const float* __restrict__ dxv,
    const unsigned short* __restrict__ WT_n1, const float* __restrict__ b_n1,
    const unsigned short* __restrict__ WT_n2, const float* __restrict__ b_n2,
    float* __restrict__ h_out, float* __restrict__ x_out)
{
    __shared__ __align__(16) unsigned short T[16*TS];

    const int lane = threadIdx.x;
    const int quad = lane >> 4;
    const int l15  = lane & 15;
    const int n0   = blockIdx.x * 16;

    if (lane < 48) {
        int r = lane / 3, c = lane % 3;
        int n = n0 + r;
        x_out[n*3 + c] = x[n*3 + c] + dxv[n*3 + c] * (float)mask[n];
    }

    const int node = n0 + l15;
    short8 a1[8];
    #pragma unroll
    for (int kc = 0; kc < 4; ++kc) {
        const float* p = agg + (size_t)node*HID + kc*32 + quad*8;
        float4 f0 = *(const float4*)(p);
        float4 f1 = *(const float4*)(p + 4);
        short8 v;
        v[0]=(short)f2bf(f0.x); v[1]=(short)f2bf(f0.y); v[2]=(short)f2bf(f0.z); v[3]=(short)f2bf(f0.w);
        v[4]=(short)f2bf(f1.x); v[5]=(short)f2bf(f1.y); v[6]=(short)f2bf(f1.z); v[7]=(short)f2bf(f1.w);
        a1[kc] = v;
    }
    #pragma unroll
    for (int kc = 0; kc < 4; ++kc)
        a1[4+kc] = *(const short8*)(h_bf + (size_t)node*HID + kc*32 + quad*8);

    floatx4 acc[8];
    #pragma unroll
    for (int t = 0; t < 8; ++t) acc[t] = (floatx4){0,0,0,0};
    #pragma unroll
    for (int kc = 0; kc < 8; ++kc) {
        #pragma unroll
        for (int t = 0; t < 8; ++t) {
            short8 b = *(const short8*)(WT_n1 + (size_t)(t*16+l15)*KN1 + kc*32 + quad*8);
            acc[t] = __builtin_amdgcn_mfma_f32_16x16x32_bf16(a1[kc], b, acc[t], 0, 0, 0);
        }
    }
    #pragma unroll
    for (int t = 0; t < 8; ++t) {
        int col = t*16 + l15;
        float bv = b_n1[col];
        #pragma unroll
        for (int i = 0; i < 4; ++i)
            T[(quad*4+i)*TS + col] = f2bf(silu_f(acc[t][i] + bv));
    }
    __builtin_amdgcn_wave_barrier();

    short8 a2[4];
    #pragma unroll
    for (int kc = 0; kc < 4; ++kc)
        a2[kc] = *(const short8*)(&T[l15*TS + kc*32 + quad*8]);
    #pragma unroll
    for (int t = 0; t < 8; ++t) acc[t] = (floatx4){0,0,0,0};
    #pragma unroll
    for (int kc = 0; kc < 4; ++kc) {
        #pragma unroll
        for (int t = 0; t < 8; ++t) {
            short8 b = *(const short8*)(WT_n2 + (size_t)(t*16+l15)*HID + kc*32 + quad*8);
            acc[t] = __builtin_amdgcn_mfma_f32_16x16x32_bf16(a2[kc], b, acc[t], 0, 0, 0);
        }
    }
    #pragma unroll
    for (int t = 0; t < 8; ++t) {
        int col = t*16 + l15;
        float bv = b_n2[col];
        #pragma unroll
        for (int i = 0; i < 4; ++i) {
            int n = n0 + quad*4 + i;
            h_out[(size_t)n*HID + col] = h[(size_t)n*HID + col] + acc[t][i] + bv;
        }
    }
}

extern "C" void kernel_launch(void* const* d_in, const int* in_sizes, int n_in,
                              void* d_out, int out_size, void* d_ws, size_t ws_size,
                              hipStream_t stream) {
    const float* h          = (const float*)d_in[0];
    const float* x          = (const float*)d_in[1];
    const float* edge_attr  = (const float*)d_in[2];
    const int*   edge_index = (const int*)  d_in[3];
    const int*   mask       = (const int*)  d_in[4];
    const float* W_e1 = (const float*)d_in[5];
    const float* b_e1 = (const float*)d_in[6];
    const float* W_e2 = (const float*)d_in[7];
    const float* b_e2 = (const float*)d_in[8];
    const float* W_g  = (const float*)d_in[9];
    const float* b_g  = (const float*)d_in[10];
    const float* W_n1 = (const float*)d_in[11];
    const float* b_n1 = (const float*)d_in[12];
    const float* W_n2 = (const float*)d_in[13];
    const float* b_n2 = (const float*)d_in[14];
    const float* W_x1 = (const float*)d_in[15];
    const float* b_x1 = (const float*)d_in[16];
    const float* W_x2 = (const float*)d_in[17];

    char* ws = (char*)d_ws;
    float* agg = (float*)ws;                       ws += (size_t)NN*HID*4;
    float* dxv = (float*)ws;                       ws += (size_t)NN*3*4;
    int*   counts = (int*)ws;                      ws += (size_t)NN*4;
    int*   cursor = (int*)ws;                      ws += (size_t)NN*4;
    int*   order  = (int*)ws;                      ws += (size_t)NE*4;
    unsigned short* h_bf  = (unsigned short*)ws;   ws += (size_t)NN*HID*2;
    unsigned short* WT_e1 = (unsigned short*)ws;   ws += (size_t)HID*K1*2;
    unsigned short* WT_e2 = (unsigned short*)ws;   ws += (size_t)HID*HID*2;
    unsigned short* WT_x1 = (unsigned short*)ws;   ws += (size_t)HID*HID*2;
    unsigned short* WT_n1 = (unsigned short*)ws;   ws += (size_t)HID*KN1*2;
    unsigned short* WT_n2 = (unsigned short*)ws;   ws += (size_t)HID*HID*2;

    hipMemsetAsync(agg, 0, ((size_t)NN*HID + (size_t)NN*3)*sizeof(float), stream);
    hipMemsetAsync(counts, 0, (size_t)NN*sizeof(int), stream);

    prep_h_kernel<<<2500, 256, 0, stream>>>(h, h_bf);
    prep_w_kernel<<<128, 320, 0, stream>>>(W_e1, W_e2, W_x1, W_n1, W_n2,
                                           WT_e1, WT_e2, WT_x1, WT_n1, WT_n2);
    hist_kernel<<<NE/256, 256, 0, stream>>>(edge_index, counts);
    scan_kernel<<<1, 256, 0, stream>>>(counts, cursor);
    scatter_kernel<<<NE/256, 256, 0, stream>>>(edge_index, cursor, order);

    egnn_edge_mfma<<<NE/16, 64, 0, stream>>>(
        x, edge_attr, edge_index, order, h_bf, WT_e1, WT_e2, WT_x1,
        b_e1, b_e2, W_g, b_g, b_x1, W_x2, agg, dxv);

    float* h_out = (float*)d_out;
    float* x_out = h_out + (size_t)NN*HID;

    egnn_node_mfma<<<NN/16, 64, 0, stream>>>(
        h, x, mask, h_bf, agg, dxv, WT_n1, b_n1, WT_n2, b_n2, h_out, x_out);
}

// Round 7
// 767.840 us; speedup vs baseline: 1.2945x; 1.2945x over previous
//
#include <hip/hip_runtime.h>
#include <math.h>

#define HID 128
#define NUM_G 20
#define EF 4
#define NN 20000
#define NE 640000
#define K1 288            // 280 padded to 9*32
#define KN1 256           // node GEMM1 K
#define TS 136            // LDS stride (bf16): 272B rows -> 2-way conflict only (free)

typedef __attribute__((ext_vector_type(8))) short short8;
typedef __attribute__((ext_vector_type(4))) short short4v;
typedef __attribute__((ext_vector_type(4))) float floatx4;

// fast activations: approx rcp (v_rcp_f32) is fine at 0.1 abs tolerance
__device__ __forceinline__ float silu_f(float v){
    return v * __builtin_amdgcn_rcpf(1.0f + __expf(-v));
}
__device__ __forceinline__ float sigm_f(float v){
    return __builtin_amdgcn_rcpf(1.0f + __expf(-v));
}
__device__ __forceinline__ float tanh_f(float v){
    return 1.0f - 2.0f * __builtin_amdgcn_rcpf(1.0f + __expf(2.0f * v));
}
__device__ __forceinline__ unsigned short f2bf(float v){
    unsigned int u = __float_as_uint(v);
    u = (u + 0x7fffu + ((u >> 16) & 1u)) >> 16;
    return (unsigned short)u;
}
__device__ __forceinline__ float bf2f(unsigned int u){
    return __uint_as_float(u << 16);
}

__global__ __launch_bounds__(256) void prep_h_kernel(
    const float* __restrict__ h, unsigned short* __restrict__ h_bf)
{
    int i = (blockIdx.x * 256 + threadIdx.x) * 4;
    float4 v = *(const float4*)(h + i);
    short4v o;
    o[0] = (short)f2bf(v.x); o[1] = (short)f2bf(v.y);
    o[2] = (short)f2bf(v.z); o[3] = (short)f2bf(v.w);
    *(short4v*)(h_bf + i) = o;
}

__global__ __launch_bounds__(320) void prep_w_kernel(
    const float* __restrict__ W_e1, const float* __restrict__ W_e2,
    const float* __restrict__ W_x1, const float* __restrict__ W_n1,
    const float* __restrict__ W_n2,
    unsigned short* __restrict__ WT_e1, unsigned short* __restrict__ WT_e2,
    unsigned short* __restrict__ WT_x1, unsigned short* __restrict__ WT_n1,
    unsigned short* __restrict__ WT_n2)
{
    int n = blockIdx.x;
    int t = threadIdx.x;
    if (t < K1)  WT_e1[n*K1  + t] = (t < 280) ? f2bf(W_e1[t*HID + n]) : (unsigned short)0;
    if (t < KN1) WT_n1[n*KN1 + t] = f2bf(W_n1[t*HID + n]);
    if (t < HID) {
        WT_e2[n*HID + t] = f2bf(W_e2[t*HID + n]);
        WT_x1[n*HID + t] = f2bf(W_x1[t*HID + n]);
        WT_n2[n*HID + t] = f2bf(W_n2[t*HID + n]);
    }
}

// ---- counting sort of edges by dst ----
__global__ __launch_bounds__(256) void hist_kernel(
    const int* __restrict__ edge_index, int* __restrict__ counts)
{
    int e = blockIdx.x * 256 + threadIdx.x;
    atomicAdd(&counts[edge_index[NE + e]], 1);
}

__global__ __launch_bounds__(256) void scan_kernel(
    const int* __restrict__ counts, int* __restrict__ cursor)
{
    __shared__ int part[256];
    const int t = threadIdx.x;
    const int CH = (NN + 255) / 256;
    int base = t * CH;
    int s = 0;
    for (int i = 0; i < CH; ++i) { int idx = base + i; if (idx < NN) s += counts[idx]; }
    part[t] = s; __syncthreads();
    for (int off = 1; off < 256; off <<= 1) {
        int v = (t >= off) ? part[t - off] : 0;
        __syncthreads();
        part[t] += v;
        __syncthreads();
    }
    int run = (t == 0) ? 0 : part[t - 1];
    for (int i = 0; i < CH; ++i) {
        int idx = base + i;
        if (idx < NN) { cursor[idx] = run; run += counts[idx]; }
    }
}

__global__ __launch_bounds__(256) void scatter_kernel(
    const int* __restrict__ edge_index, int* __restrict__ cursor,
    int* __restrict__ order)
{
    int e = blockIdx.x * 256 + threadIdx.x;
    int d = edge_index[NE + e];
    int pos = atomicAdd(&cursor[d], 1);
    order[pos] = e;
}

// ---- edge kernel: 256 threads = 4 AUTONOMOUS waves, each owns 16 sorted edges.
// No __syncthreads; per-wave LDS slices. Workgroup-cap (≈16 wg/CU) no longer
// binds occupancy since each wg carries 4 waves.
__global__ __launch_bounds__(256, 4) void egnn_edge_mfma(
    const float* __restrict__ x, const float* __restrict__ edge_attr,
    const int* __restrict__ edge_index, const int* __restrict__ order,
    const unsigned short* __restrict__ h_bf,
    const unsigned short* __restrict__ WT_e1,
    const unsigned short* __restrict__ WT_e2,
    const unsigned short* __restrict__ WT_x1,
    const float* __restrict__ b_e1, const float* __restrict__ b_e2,
    const float* __restrict__ W_g,  const float* __restrict__ b_g,
    const float* __restrict__ b_x1, const float* __restrict__ W_x2,
    float* __restrict__ agg, float* __restrict__ dxv)
{
    __shared__ __align__(16) unsigned short T[4][16*TS];   // m1, then m2 (per wave)
    __shared__ int   s_dst[4][17];                         // [16] = -1 sentinel
    __shared__ float s_g[4][16];
    __shared__ float s_vec[4][48];

    const int wv   = threadIdx.x >> 6;
    const int lane = threadIdx.x & 63;
    const int quad = lane >> 4;
    const int l15  = lane & 15;
    const int e0   = (blockIdx.x * 4 + wv) * 16;

    unsigned short* Tw = &T[wv][0];

    // --- meta in registers (lanes 0..15 own one edge each) ---
    int   ereg = 0, sreg = 0, dreg = 0;
    float rxr = 0.f, ryr = 0.f, rzr = 0.f, rreg = 0.f;
    if (lane < 16) {
        ereg = order[e0 + lane];
        sreg = edge_index[ereg];
        dreg = edge_index[NE + ereg];
        rxr = x[dreg*3+0] - x[sreg*3+0];
        ryr = x[dreg*3+1] - x[sreg*3+1];
        rzr = x[dreg*3+2] - x[sreg*3+2];
        rreg = sqrtf(rxr*rxr + ryr*ryr + rzr*rzr + 1e-8f);
        s_dst[wv][lane] = dreg;
    }
    if (lane == 16) s_dst[wv][16] = -1;

    // broadcast row-l15 meta to all quads
    const int   nd  = __shfl(dreg, l15);
    const int   ns  = __shfl(sreg, l15);
    const int   eid = __shfl(ereg, l15);
    const float rr  = __shfl(rreg, l15);

    // --- GEMM1 A-fragments: direct global gather + in-register RBF ---
    const unsigned short* hd = h_bf + (size_t)nd*HID + quad*8;
    const unsigned short* hs = h_bf + (size_t)ns*HID + quad*8;
    short8 a1[9];
    #pragma unroll
    for (int kc = 0; kc < 4; ++kc) a1[kc]   = *(const short8*)(hd + kc*32);
    #pragma unroll
    for (int kc = 0; kc < 4; ++kc) a1[4+kc] = *(const short8*)(hs + kc*32);
    {
        const float step  = 10.0f / 19.0f;
        const float coeff = -0.5f / (step*step);
        short8 v;
        #pragma unroll
        for (int j = 0; j < 8; ++j) {
            int col = quad*8 + j;     // 0..31 within the last K-chunk (256..287 overall)
            float val = 0.f;
            if (col < NUM_G) {
                float d = rr - step*(float)col;
                val = __expf(coeff*d*d);
            } else if (col < NUM_G+EF) {
                val = edge_attr[(size_t)eid*EF + (col-NUM_G)];
            }
            v[j] = (short)f2bf(val);
        }
        a1[8] = v;
    }

    floatx4 acc[8];
    #pragma unroll
    for (int t = 0; t < 8; ++t) acc[t] = (floatx4){0,0,0,0};
    #pragma unroll
    for (int kc = 0; kc < 9; ++kc) {
        #pragma unroll
        for (int t = 0; t < 8; ++t) {
            short8 b = *(const short8*)(WT_e1 + (size_t)(t*16+l15)*K1 + kc*32 + quad*8);
            acc[t] = __builtin_amdgcn_mfma_f32_16x16x32_bf16(a1[kc], b, acc[t], 0, 0, 0);
        }
    }
    // epilogue 1: m1 = silu(acc + b_e1) -> T
    #pragma unroll
    for (int t = 0; t < 8; ++t) {
        int col = t*16 + l15;
        float bv = b_e1[col];
        #pragma unroll
        for (int i = 0; i < 4; ++i)
            Tw[(quad*4+i)*TS + col] = f2bf(silu_f(acc[t][i] + bv));
    }
    __builtin_amdgcn_wave_barrier();

    // --- GEMM2: m2 = silu(m1 @ W_e2 + b), gate ---
    short8 a2[4];
    #pragma unroll
    for (int kc = 0; kc < 4; ++kc)
        a2[kc] = *(const short8*)(&Tw[l15*TS + kc*32 + quad*8]);
    #pragma unroll
    for (int t = 0; t < 8; ++t) acc[t] = (floatx4){0,0,0,0};
    #pragma unroll
    for (int kc = 0; kc < 4; ++kc) {
        #pragma unroll
        for (int t = 0; t < 8; ++t) {
            short8 b = *(const short8*)(WT_e2 + (size_t)(t*16+l15)*HID + kc*32 + quad*8);
            acc[t] = __builtin_amdgcn_mfma_f32_16x16x32_bf16(a2[kc], b, acc[t], 0, 0, 0);
        }
    }
    {
        float gp[4] = {0,0,0,0};
        #pragma unroll
        for (int t = 0; t < 8; ++t) {
            int col = t*16 + l15;
            float bv = b_e2[col];
            float wgv = W_g[col];
            #pragma unroll
            for (int i = 0; i < 4; ++i) {
                float m2 = silu_f(acc[t][i] + bv);
                gp[i] += m2 * wgv;
                Tw[(quad*4+i)*TS + col] = f2bf(m2);   // overwrite m1 with m2
            }
        }
        const float bg0 = b_g[0];
        #pragma unroll
        for (int i = 0; i < 4; ++i) {
            gp[i] += __shfl_xor(gp[i], 1);
            gp[i] += __shfl_xor(gp[i], 2);
            gp[i] += __shfl_xor(gp[i], 4);
            gp[i] += __shfl_xor(gp[i], 8);
        }
        if (l15 == 0) {
            #pragma unroll
            for (int i = 0; i < 4; ++i) s_g[wv][quad*4 + i] = sigm_f(gp[i] + bg0);
        }
    }
    __builtin_amdgcn_wave_barrier();

    // --- GEMM3: coord head (before any atomics) ---
    short8 a3[4];
    #pragma unroll
    for (int kc = 0; kc < 4; ++kc)
        a3[kc] = *(const short8*)(&Tw[l15*TS + kc*32 + quad*8]);
    #pragma unroll
    for (int t = 0; t < 8; ++t) acc[t] = (floatx4){0,0,0,0};
    #pragma unroll
    for (int kc = 0; kc < 4; ++kc) {
        #pragma unroll
        for (int t = 0; t < 8; ++t) {
            short8 b = *(const short8*)(WT_x1 + (size_t)(t*16+l15)*HID + kc*32 + quad*8);
            acc[t] = __builtin_amdgcn_mfma_f32_16x16x32_bf16(a3[kc], b, acc[t], 0, 0, 0);
        }
    }
    {
        float cp[4] = {0,0,0,0};
        #pragma unroll
        for (int t = 0; t < 8; ++t) {
            int col = t*16 + l15;
            float bv = b_x1[col];
            float wx = W_x2[col];
            #pragma unroll
            for (int i = 0; i < 4; ++i)
                cp[i] += silu_f(acc[t][i] + bv) * wx;
        }
        #pragma unroll
        for (int i = 0; i < 4; ++i) {
            cp[i] += __shfl_xor(cp[i], 1);
            cp[i] += __shfl_xor(cp[i], 2);
            cp[i] += __shfl_xor(cp[i], 4);
            cp[i] += __shfl_xor(cp[i], 8);
        }
        if (l15 < 3) {
            #pragma unroll
            for (int i = 0; i < 4; ++i) {
                int row = quad*4 + i;
                float rxv = __shfl(rxr, row);
                float ryv = __shfl(ryr, row);
                float rzv = __shfl(rzr, row);
                float rv  = __shfl(rreg, row);
                float relc = (l15 == 0) ? rxv : ((l15 == 1) ? ryv : rzv);
                s_vec[wv][row*3 + l15] = relc * __builtin_amdgcn_rcpf(rv + 1.0f) * tanh_f(cp[i]);
            }
        }
    }
    __builtin_amdgcn_wave_barrier();

    // --- ALL scatters at the very end ---
    {
        float am0 = 0.f, am1 = 0.f;
        #pragma unroll
        for (int r = 0; r < 16; ++r) {
            unsigned int pv = *(const unsigned int*)(&Tw[r*TS + lane*2]);
            float gr = s_g[wv][r];
            am0 += bf2f(pv & 0xffffu) * gr;
            am1 += bf2f(pv >> 16) * gr;
            int dr = s_dst[wv][r];
            if (dr != s_dst[wv][r+1]) {
                atomicAdd(&agg[(size_t)dr*HID + lane*2],     am0);
                atomicAdd(&agg[(size_t)dr*HID + lane*2 + 1], am1);
                am0 = 0.f; am1 = 0.f;
            }
        }
    }
    if (lane < 3) {
        float a = 0.f;
        #pragma unroll
        for (int r = 0; r < 16; ++r) {
            a += s_vec[wv][r*3 + lane];
            int dr = s_dst[wv][r];
            if (dr != s_dst[wv][r+1]) {
                atomicAdd(&dxv[(size_t)dr*3 + lane], a);
                a = 0.f;
            }
        }
    }
}

// ---- node kernel: ONE WAVE per block, 16 nodes ----
__global__ __launch_bounds__(64, 4) void egnn_node_mfma(
    const float* __restrict__ h, const float* __restrict__ x,
    const int* __restrict__ mask,
    const unsigned short* __restrict__ h_bf,
    const float* __restrict__ agg, const float* __restrict__ dxv,
    const unsigned short* __restrict__ WT_n1, const float* __restrict__ b_n1,
    const unsigned short* __restrict__ WT_n2, const float* __restrict__ b_n2,
    float* __restrict__ h_out, float* __restrict__ x_out)
{
    __shared__ __align__(16) unsigned short T[16*TS];

    const int lane = threadIdx.x;
    const int quad = lane >> 4;
    const int l15  = lane & 15;
    const int n0   = blockIdx.x * 16;

    if (lane < 48) {
        int r = lane / 3, c = lane % 3;
        int n = n0 + r;
        x_out[n*3 + c] = x[n*3 + c] + dxv[n*3 + c] * (float)mask[n];
    }

    const int node = n0 + l15;
    short8 a1[8];
    #pragma unroll
    for (int kc = 0; kc < 4; ++kc) {
        const float* p = agg + (size_t)node*HID + kc*32 + quad*8;
        float4 f0 = *(const float4*)(p);
        float4 f1 = *(const float4*)(p + 4);
        short8 v;
        v[0]=(short)f2bf(f0.x); v[1]=(short)f2bf(f0.y); v[2]=(short)f2bf(f0.z); v[3]=(short)f2bf(f0.w);
        v[4]=(short)f2bf(f1.x); v[5]=(short)f2bf(f1.y); v[6]=(short)f2bf(f1.z); v[7]=(short)f2bf(f1.w);
        a1[kc] = v;
    }
    #pragma unroll
    for (int kc = 0; kc < 4; ++kc)
        a1[4+kc] = *(const short8*)(h_bf + (size_t)node*HID + kc*32 + quad*8);

    floatx4 acc[8];
    #pragma unroll
    for (int t = 0; t < 8; ++t) acc[t] = (floatx4){0,0,0,0};
    #pragma unroll
    for (int kc = 0; kc < 8; ++kc) {
        #pragma unroll
        for (int t = 0; t < 8; ++t) {
            short8 b = *(const short8*)(WT_n1 + (size_t)(t*16+l15)*KN1 + kc*32 + quad*8);
            acc[t] = __builtin_amdgcn_mfma_f32_16x16x32_bf16(a1[kc], b, acc[t], 0, 0, 0);
        }
    }
    #pragma unroll
    for (int t = 0; t < 8; ++t) {
        int col = t*16 + l15;
        float bv = b_n1[col];
        #pragma unroll
        for (int i = 0; i < 4; ++i)
            T[(quad*4+i)*TS + col] = f2bf(silu_f(acc[t][i] + bv));
    }
    __builtin_amdgcn_wave_barrier();

    short8 a2[4];
    #pragma unroll
    for (int kc = 0; kc < 4; ++kc)
        a2[kc] = *(const short8*)(&T[l15*TS + kc*32 + quad*8]);
    #pragma unroll
    for (int t = 0; t < 8; ++t) acc[t] = (floatx4){0,0,0,0};
    #pragma unroll
    for (int kc = 0; kc < 4; ++kc) {
        #pragma unroll
        for (int t = 0; t < 8; ++t) {
            short8 b = *(const short8*)(WT_n2 + (size_t)(t*16+l15)*HID + kc*32 + quad*8);
            acc[t] = __builtin_amdgcn_mfma_f32_16x16x32_bf16(a2[kc], b, acc[t], 0, 0, 0);
        }
    }
    #pragma unroll
    for (int t = 0; t < 8; ++t) {
        int col = t*16 + l15;
        float bv = b_n2[col];
        #pragma unroll
        for (int i = 0; i < 4; ++i) {
            int n = n0 + quad*4 + i;
            h_out[(size_t)n*HID + col] = h[(size_t)n*HID + col] + acc[t][i] + bv;
        }
    }
}

extern "C" void kernel_launch(void* const* d_in, const int* in_sizes, int n_in,
                              void* d_out, int out_size, void* d_ws, size_t ws_size,
                              hipStream_t stream) {
    const float* h          = (const float*)d_in[0];
    const float* x          = (const float*)d_in[1];
    const float* edge_attr  = (const float*)d_in[2];
    const int*   edge_index = (const int*)  d_in[3];
    const int*   mask       = (const int*)  d_in[4];
    const float* W_e1 = (const float*)d_in[5];
    const float* b_e1 = (const float*)d_in[6];
    const float* W_e2 = (const float*)d_in[7];
    const float* b_e2 = (const float*)d_in[8];
    const float* W_g  = (const float*)d_in[9];
    const float* b_g  = (const float*)d_in[10];
    const float* W_n1 = (const float*)d_in[11];
    const float* b_n1 = (const float*)d_in[12];
    const float* W_n2 = (const float*)d_in[13];
    const float* b_n2 = (const float*)d_in[14];
    const float* W_x1 = (const float*)d_in[15];
    const float* b_x1 = (const float*)d_in[16];
    const float* W_x2 = (const float*)d_in[17];

    char* ws = (char*)d_ws;
    float* agg = (float*)ws;                       ws += (size_t)NN*HID*4;
    float* dxv = (float*)ws;                       ws += (size_t)NN*3*4;
    int*   counts = (int*)ws;                      ws += (size_t)NN*4;
    int*   cursor = (int*)ws;                      ws += (size_t)NN*4;
    int*   order  = (int*)ws;                      ws += (size_t)NE*4;
    unsigned short* h_bf  = (unsigned short*)ws;   ws += (size_t)NN*HID*2;
    unsigned short* WT_e1 = (unsigned short*)ws;   ws += (size_t)HID*K1*2;
    unsigned short* WT_e2 = (unsigned short*)ws;   ws += (size_t)HID*HID*2;
    unsigned short* WT_x1 = (unsigned short*)ws;   ws += (size_t)HID*HID*2;
    unsigned short* WT_n1 = (unsigned short*)ws;   ws += (size_t)HID*KN1*2;
    unsigned short* WT_n2 = (unsigned short*)ws;   ws += (size_t)HID*HID*2;

    hipMemsetAsync(agg, 0, ((size_t)NN*HID + (size_t)NN*3)*sizeof(float), stream);
    hipMemsetAsync(counts, 0, (size_t)NN*sizeof(int), stream);

    prep_h_kernel<<<2500, 256, 0, stream>>>(h, h_bf);
    prep_w_kernel<<<128, 320, 0, stream>>>(W_e1, W_e2, W_x1, W_n1, W_n2,
                                           WT_e1, WT_e2, WT_x1, WT_n1, WT_n2);
    hist_kernel<<<NE/256, 256, 0, stream>>>(edge_index, counts);
    scan_kernel<<<1, 256, 0, stream>>>(counts, cursor);
    scatter_kernel<<<NE/256, 256, 0, stream>>>(edge_index, cursor, order);

    egnn_edge_mfma<<<NE/64, 256, 0, stream>>>(
        x, edge_attr, edge_index, order, h_bf, WT_e1, WT_e2, WT_x1,
        b_e1, b_e2, W_g, b_g, b_x1, W_x2, agg, dxv);

    float* h_out = (float*)d_out;
    float* x_out = h_out + (size_t)NN*HID;

    egnn_node_mfma<<<NN/16, 64, 0, stream>>>(
        h, x, mask, h_bf, agg, dxv, WT_n1, b_n1, WT_n2, b_n2, h_out, x_out);
}

// Round 8
// 596.992 us; speedup vs baseline: 1.6650x; 1.2862x over previous
//
#include <hip/hip_runtime.h>
#include <math.h>

#define HID 128
#define NUM_G 20
#define EF 4
#define NN 20000
#define NE 640000
#define KN1 256           // node GEMM1 K
#define TS 136            // LDS stride (bf16): 272B rows -> 2-way conflict only (free)

typedef __attribute__((ext_vector_type(8))) short short8;
typedef __attribute__((ext_vector_type(4))) short short4v;
typedef __attribute__((ext_vector_type(4))) float floatx4;

// fast activations: approx rcp (v_rcp_f32) is fine at 0.1 abs tolerance
__device__ __forceinline__ float silu_f(float v){
    return v * __builtin_amdgcn_rcpf(1.0f + __expf(-v));
}
__device__ __forceinline__ float sigm_f(float v){
    return __builtin_amdgcn_rcpf(1.0f + __expf(-v));
}
__device__ __forceinline__ float tanh_f(float v){
    return 1.0f - 2.0f * __builtin_amdgcn_rcpf(1.0f + __expf(2.0f * v));
}
__device__ __forceinline__ unsigned short f2bf(float v){
    unsigned int u = __float_as_uint(v);
    u = (u + 0x7fffu + ((u >> 16) & 1u)) >> 16;
    return (unsigned short)u;
}
__device__ __forceinline__ float bf2f(unsigned short u){
    return __uint_as_float(((unsigned int)u) << 16);
}

// transpose + bf16-ify weights.
// WT1d[c][k] = W_e1[k][c]       (k<128)   -> PD precompute
// WT1s[c][k] = W_e1[128+k][c]   (k<128)   -> PS precompute
// WT1r[c][k] = W_e1[256+k][c]   (k<24, pad to 32) -> edge rbf GEMM
__global__ __launch_bounds__(320) void prep_w_kernel(
    const float* __restrict__ W_e1, const float* __restrict__ W_e2,
    const float* __restrict__ W_x1, const float* __restrict__ W_n1,
    const float* __restrict__ W_n2,
    unsigned short* __restrict__ WT1d, unsigned short* __restrict__ WT1s,
    unsigned short* __restrict__ WT1r,
    unsigned short* __restrict__ WT_e2, unsigned short* __restrict__ WT_x1,
    unsigned short* __restrict__ WT_n1, unsigned short* __restrict__ WT_n2)
{
    int n = blockIdx.x;   // output channel c
    int t = threadIdx.x;  // k index
    if (t < HID) {
        WT1d[n*HID + t] = f2bf(W_e1[t*HID + n]);
        WT1s[n*HID + t] = f2bf(W_e1[(HID+t)*HID + n]);
        WT_e2[n*HID + t] = f2bf(W_e2[t*HID + n]);
        WT_x1[n*HID + t] = f2bf(W_x1[t*HID + n]);
        WT_n2[n*HID + t] = f2bf(W_n2[t*HID + n]);
    }
    if (t < 32) WT1r[n*32 + t] = (t < NUM_G+EF) ? f2bf(W_e1[(256+t)*HID + n]) : (unsigned short)0;
    if (t < KN1) WT_n1[n*KN1 + t] = f2bf(W_n1[t*HID + n]);
}

// ---- counting sort of edges by dst ----
__global__ __launch_bounds__(256) void hist_kernel(
    const int* __restrict__ edge_index, int* __restrict__ counts)
{
    int e = blockIdx.x * 256 + threadIdx.x;
    atomicAdd(&counts[edge_index[NE + e]], 1);
}

__global__ __launch_bounds__(1024) void scan_kernel(
    const int* __restrict__ counts, int* __restrict__ cursor)
{
    __shared__ int part[1024];
    const int t = threadIdx.x;
    const int CH = (NN + 1023) / 1024;   // 20
    int base = t * CH;
    int s = 0;
    for (int i = 0; i < CH; ++i) { int idx = base + i; if (idx < NN) s += counts[idx]; }
    part[t] = s; __syncthreads();
    for (int off = 1; off < 1024; off <<= 1) {
        int v = (t >= off) ? part[t - off] : 0;
        __syncthreads();
        part[t] += v;
        __syncthreads();
    }
    int run = (t == 0) ? 0 : part[t - 1];
    for (int i = 0; i < CH; ++i) {
        int idx = base + i;
        if (idx < NN) { cursor[idx] = run; run += counts[idx]; }
    }
}

__global__ __launch_bounds__(256) void scatter_kernel(
    const int* __restrict__ edge_index, int* __restrict__ cursor,
    int* __restrict__ order)
{
    int e = blockIdx.x * 256 + threadIdx.x;
    int d = edge_index[NE + e];
    int pos = atomicAdd(&cursor[d], 1);
    order[pos] = e;
}

// ---- PD/PS precompute: PD[n] = h[n]@W1d + b_e1, PS[n] = h[n]@W1s (bf16 out) ----
__global__ __launch_bounds__(64, 4) void pd_kernel(
    const float* __restrict__ h, const float* __restrict__ b_e1,
    const unsigned short* __restrict__ WT1d, const unsigned short* __restrict__ WT1s,
    unsigned short* __restrict__ PD, unsigned short* __restrict__ PS)
{
    __shared__ __align__(16) unsigned short T[16*TS];

    const int lane = threadIdx.x;
    const int quad = lane >> 4;
    const int l15  = lane & 15;
    const int n0   = blockIdx.x * 16;
    const int node = n0 + l15;

    short8 ah[4];
    #pragma unroll
    for (int kc = 0; kc < 4; ++kc) {
        const float* p = h + (size_t)node*HID + kc*32 + quad*8;
        float4 f0 = *(const float4*)(p);
        float4 f1 = *(const float4*)(p + 4);
        short8 v;
        v[0]=(short)f2bf(f0.x); v[1]=(short)f2bf(f0.y); v[2]=(short)f2bf(f0.z); v[3]=(short)f2bf(f0.w);
        v[4]=(short)f2bf(f1.x); v[5]=(short)f2bf(f1.y); v[6]=(short)f2bf(f1.z); v[7]=(short)f2bf(f1.w);
        ah[kc] = v;
    }

    floatx4 ad[8], as[8];
    #pragma unroll
    for (int t = 0; t < 8; ++t) { ad[t] = (floatx4){0,0,0,0}; as[t] = (floatx4){0,0,0,0}; }
    #pragma unroll
    for (int kc = 0; kc < 4; ++kc) {
        #pragma unroll
        for (int t = 0; t < 8; ++t) {
            short8 bd = *(const short8*)(WT1d + (size_t)(t*16+l15)*HID + kc*32 + quad*8);
            short8 bs = *(const short8*)(WT1s + (size_t)(t*16+l15)*HID + kc*32 + quad*8);
            ad[t] = __builtin_amdgcn_mfma_f32_16x16x32_bf16(ah[kc], bd, ad[t], 0, 0, 0);
            as[t] = __builtin_amdgcn_mfma_f32_16x16x32_bf16(ah[kc], bs, as[t], 0, 0, 0);
        }
    }
    // PD (bias folded) via LDS transpose
    #pragma unroll
    for (int t = 0; t < 8; ++t) {
        int col = t*16 + l15;
        float bv = b_e1[col];
        #pragma unroll
        for (int i = 0; i < 4; ++i)
            T[(quad*4+i)*TS + col] = f2bf(ad[t][i] + bv);
    }
    __builtin_amdgcn_wave_barrier();
    #pragma unroll
    for (int kc = 0; kc < 4; ++kc)
        *(short8*)(PD + (size_t)node*HID + kc*32 + quad*8) =
            *(const short8*)(&T[l15*TS + kc*32 + quad*8]);
    __builtin_amdgcn_wave_barrier();
    // PS
    #pragma unroll
    for (int t = 0; t < 8; ++t) {
        int col = t*16 + l15;
        #pragma unroll
        for (int i = 0; i < 4; ++i)
            T[(quad*4+i)*TS + col] = f2bf(as[t][i]);
    }
    __builtin_amdgcn_wave_barrier();
    #pragma unroll
    for (int kc = 0; kc < 4; ++kc)
        *(short8*)(PS + (size_t)node*HID + kc*32 + quad*8) =
            *(const short8*)(&T[l15*TS + kc*32 + quad*8]);
}

// ---- edge kernel: 4 autonomous waves/block, 16 sorted edges/wave, GEMM1 deleted ----
__global__ __launch_bounds__(256, 3) void egnn_edge_mfma(
    const float* __restrict__ x, const float* __restrict__ edge_attr,
    const int* __restrict__ edge_index, const int* __restrict__ order,
    const unsigned short* __restrict__ PD, const unsigned short* __restrict__ PS,
    const unsigned short* __restrict__ WT1r,
    const unsigned short* __restrict__ WT_e2,
    const unsigned short* __restrict__ WT_x1,
    const float* __restrict__ b_e2,
    const float* __restrict__ W_g,  const float* __restrict__ b_g,
    const float* __restrict__ b_x1, const float* __restrict__ W_x2,
    float* __restrict__ agg, float* __restrict__ dxv)
{
    __shared__ __align__(16) unsigned short T[4][16*TS];   // rbf-acc, then m2
    __shared__ int   s_dst[4][17];
    __shared__ float s_g[4][16];
    __shared__ float s_vec[4][48];

    const int wv   = threadIdx.x >> 6;
    const int lane = threadIdx.x & 63;
    const int quad = lane >> 4;
    const int l15  = lane & 15;
    const int e0   = (blockIdx.x * 4 + wv) * 16;

    unsigned short* Tw = &T[wv][0];

    // --- meta in registers ---
    int   ereg = 0, sreg = 0, dreg = 0;
    float rxr = 0.f, ryr = 0.f, rzr = 0.f, rreg = 0.f;
    if (lane < 16) {
        ereg = order[e0 + lane];
        sreg = edge_index[ereg];
        dreg = edge_index[NE + ereg];
        rxr = x[dreg*3+0] - x[sreg*3+0];
        ryr = x[dreg*3+1] - x[sreg*3+1];
        rzr = x[dreg*3+2] - x[sreg*3+2];
        rreg = sqrtf(rxr*rxr + ryr*ryr + rzr*rzr + 1e-8f);
        s_dst[wv][lane] = dreg;
    }
    if (lane == 16) s_dst[wv][16] = -1;

    const int   nd  = __shfl(dreg, l15);
    const int   ns  = __shfl(sreg, l15);
    const int   eid = __shfl(ereg, l15);
    const float rr  = __shfl(rreg, l15);

    // early gathers: PD[dst], PS[src] rows in A-layout (bf16, 16B each)
    short8 pdv[4], psv[4];
    #pragma unroll
    for (int kc = 0; kc < 4; ++kc) {
        pdv[kc] = *(const short8*)(PD + (size_t)nd*HID + kc*32 + quad*8);
        psv[kc] = *(const short8*)(PS + (size_t)ns*HID + kc*32 + quad*8);
    }

    // rbf fragment (K-chunk 0..31 -> cols 256..287 of original m_in)
    short8 ar;
    {
        const float step  = 10.0f / 19.0f;
        const float coeff = -0.5f / (step*step);
        #pragma unroll
        for (int j = 0; j < 8; ++j) {
            int col = quad*8 + j;
            float val = 0.f;
            if (col < NUM_G) {
                float d = rr - step*(float)col;
                val = __expf(coeff*d*d);
            } else if (col < NUM_G+EF) {
                val = edge_attr[(size_t)eid*EF + (col-NUM_G)];
            }
            ar[j] = (short)f2bf(val);
        }
    }

    floatx4 acc[8];
    #pragma unroll
    for (int t = 0; t < 8; ++t) acc[t] = (floatx4){0,0,0,0};
    #pragma unroll
    for (int t = 0; t < 8; ++t) {
        short8 b = *(const short8*)(WT1r + (size_t)(t*16+l15)*32 + quad*8);
        acc[t] = __builtin_amdgcn_mfma_f32_16x16x32_bf16(ar, b, acc[t], 0, 0, 0);
    }
    // raw rbf contribution -> T (C-layout, bf16)
    #pragma unroll
    for (int t = 0; t < 8; ++t) {
        int col = t*16 + l15;
        #pragma unroll
        for (int i = 0; i < 4; ++i)
            Tw[(quad*4+i)*TS + col] = f2bf(acc[t][i]);
    }
    __builtin_amdgcn_wave_barrier();

    // layer-1 finalize in registers: m1 = silu(PD[dst]+PS[src]+rbf)  (bias in PD)
    short8 a2[4];
    #pragma unroll
    for (int kc = 0; kc < 4; ++kc) {
        short8 rv = *(const short8*)(&Tw[l15*TS + kc*32 + quad*8]);
        short8 o;
        #pragma unroll
        for (int j = 0; j < 8; ++j) {
            float v = bf2f((unsigned short)pdv[kc][j])
                    + bf2f((unsigned short)psv[kc][j])
                    + bf2f((unsigned short)rv[j]);
            o[j] = (short)f2bf(silu_f(v));
        }
        a2[kc] = o;
    }
    __builtin_amdgcn_wave_barrier();

    // --- GEMM2: m2 = silu(m1 @ W_e2 + b), gate ---
    #pragma unroll
    for (int t = 0; t < 8; ++t) acc[t] = (floatx4){0,0,0,0};
    #pragma unroll
    for (int kc = 0; kc < 4; ++kc) {
        #pragma unroll
        for (int t = 0; t < 8; ++t) {
            short8 b = *(const short8*)(WT_e2 + (size_t)(t*16+l15)*HID + kc*32 + quad*8);
            acc[t] = __builtin_amdgcn_mfma_f32_16x16x32_bf16(a2[kc], b, acc[t], 0, 0, 0);
        }
    }
    {
        float gp[4] = {0,0,0,0};
        #pragma unroll
        for (int t = 0; t < 8; ++t) {
            int col = t*16 + l15;
            float bv = b_e2[col];
            float wgv = W_g[col];
            #pragma unroll
            for (int i = 0; i < 4; ++i) {
                float m2 = silu_f(acc[t][i] + bv);
                gp[i] += m2 * wgv;
                Tw[(quad*4+i)*TS + col] = f2bf(m2);   // overwrite rbf with m2
            }
        }
        const float bg0 = b_g[0];
        #pragma unroll
        for (int i = 0; i < 4; ++i) {
            gp[i] += __shfl_xor(gp[i], 1);
            gp[i] += __shfl_xor(gp[i], 2);
            gp[i] += __shfl_xor(gp[i], 4);
            gp[i] += __shfl_xor(gp[i], 8);
        }
        if (l15 == 0) {
            #pragma unroll
            for (int i = 0; i < 4; ++i) s_g[wv][quad*4 + i] = sigm_f(gp[i] + bg0);
        }
    }
    __builtin_amdgcn_wave_barrier();

    // --- GEMM3: coord head ---
    short8 a3[4];
    #pragma unroll
    for (int kc = 0; kc < 4; ++kc)
        a3[kc] = *(const short8*)(&Tw[l15*TS + kc*32 + quad*8]);
    #pragma unroll
    for (int t = 0; t < 8; ++t) acc[t] = (floatx4){0,0,0,0};
    #pragma unroll
    for (int kc = 0; kc < 4; ++kc) {
        #pragma unroll
        for (int t = 0; t < 8; ++t) {
            short8 b = *(const short8*)(WT_x1 + (size_t)(t*16+l15)*HID + kc*32 + quad*8);
            acc[t] = __builtin_amdgcn_mfma_f32_16x16x32_bf16(a3[kc], b, acc[t], 0, 0, 0);
        }
    }
    {
        float cp[4] = {0,0,0,0};
        #pragma unroll
        for (int t = 0; t < 8; ++t) {
            int col = t*16 + l15;
            float bv = b_x1[col];
            float wx = W_x2[col];
            #pragma unroll
            for (int i = 0; i < 4; ++i)
                cp[i] += silu_f(acc[t][i] + bv) * wx;
        }
        #pragma unroll
        for (int i = 0; i < 4; ++i) {
            cp[i] += __shfl_xor(cp[i], 1);
            cp[i] += __shfl_xor(cp[i], 2);
            cp[i] += __shfl_xor(cp[i], 4);
            cp[i] += __shfl_xor(cp[i], 8);
        }
        if (l15 < 3) {
            #pragma unroll
            for (int i = 0; i < 4; ++i) {
                int row = quad*4 + i;
                float rxv = __shfl(rxr, row);
                float ryv = __shfl(ryr, row);
                float rzv = __shfl(rzr, row);
                float rv  = __shfl(rreg, row);
                float relc = (l15 == 0) ? rxv : ((l15 == 1) ? ryv : rzv);
                s_vec[wv][row*3 + l15] = relc * __builtin_amdgcn_rcpf(rv + 1.0f) * tanh_f(cp[i]);
            }
        }
    }
    __builtin_amdgcn_wave_barrier();

    // --- scatters last ---
    {
        float am0 = 0.f, am1 = 0.f;
        #pragma unroll
        for (int r = 0; r < 16; ++r) {
            unsigned int pv = *(const unsigned int*)(&Tw[r*TS + lane*2]);
            float gr = s_g[wv][r];
            am0 += bf2f((unsigned short)(pv & 0xffffu)) * gr;
            am1 += bf2f((unsigned short)(pv >> 16)) * gr;
            int dr = s_dst[wv][r];
            if (dr != s_dst[wv][r+1]) {
                atomicAdd(&agg[(size_t)dr*HID + lane*2],     am0);
                atomicAdd(&agg[(size_t)dr*HID + lane*2 + 1], am1);
                am0 = 0.f; am1 = 0.f;
            }
        }
    }
    if (lane < 3) {
        float a = 0.f;
        #pragma unroll
        for (int r = 0; r < 16; ++r) {
            a += s_vec[wv][r*3 + lane];
            int dr = s_dst[wv][r];
            if (dr != s_dst[wv][r+1]) {
                atomicAdd(&dxv[(size_t)dr*3 + lane], a);
                a = 0.f;
            }
        }
    }
}

// ---- node kernel: ONE WAVE per block, 16 nodes ----
__global__ __launch_bounds__(64, 4) void egnn_node_mfma(
    const float* __restrict__ h, const float* __restrict__ x,
    const int* __restrict__ mask,
    const float* __restrict__ agg, const float* __restrict__ dxv,
    const unsigned short* __restrict__ WT_n1, const float* __restrict__ b_n1,
    const unsigned short* __restrict__ WT_n2, const float* __restrict__ b_n2,
    float* __restrict__ h_out, float* __restrict__ x_out)
{
    __shared__ __align__(16) unsigned short T[16*TS];

    const int lane = threadIdx.x;
    const int quad = lane >> 4;
    const int l15  = lane & 15;
    const int n0   = blockIdx.x * 16;

    if (lane < 48) {
        int r = lane / 3, c = lane % 3;
        int n = n0 + r;
        x_out[n*3 + c] = x[n*3 + c] + dxv[n*3 + c] * (float)mask[n];
    }

    const int node = n0 + l15;
    short8 a1[8];
    #pragma unroll
    for (int kc = 0; kc < 4; ++kc) {
        const float* p = agg + (size_t)node*HID + kc*32 + quad*8;
        float4 f0 = *(const float4*)(p);
        float4 f1 = *(const float4*)(p + 4);
        short8 v;
        v[0]=(short)f2bf(f0.x); v[1]=(short)f2bf(f0.y); v[2]=(short)f2bf(f0.z); v[3]=(short)f2bf(f0.w);
        v[4]=(short)f2bf(f1.x); v[5]=(short)f2bf(f1.y); v[6]=(short)f2bf(f1.z); v[7]=(short)f2bf(f1.w);
        a1[kc] = v;
    }
    #pragma unroll
    for (int kc = 0; kc < 4; ++kc) {
        const float* p = h + (size_t)node*HID + kc*32 + quad*8;
        float4 f0 = *(const float4*)(p);
        float4 f1 = *(const float4*)(p + 4);
        short8 v;
        v[0]=(short)f2bf(f0.x); v[1]=(short)f2bf(f0.y); v[2]=(short)f2bf(f0.z); v[3]=(short)f2bf(f0.w);
        v[4]=(short)f2bf(f1.x); v[5]=(short)f2bf(f1.y); v[6]=(short)f2bf(f1.z); v[7]=(short)f2bf(f1.w);
        a1[4+kc] = v;
    }

    floatx4 acc[8];
    #pragma unroll
    for (int t = 0; t < 8; ++t) acc[t] = (floatx4){0,0,0,0};
    #pragma unroll
    for (int kc = 0; kc < 8; ++kc) {
        #pragma unroll
        for (int t = 0; t < 8; ++t) {
            short8 b = *(const short8*)(WT_n1 + (size_t)(t*16+l15)*KN1 + kc*32 + quad*8);
            acc[t] = __builtin_amdgcn_mfma_f32_16x16x32_bf16(a1[kc], b, acc[t], 0, 0, 0);
        }
    }
    #pragma unroll
    for (int t = 0; t < 8; ++t) {
        int col = t*16 + l15;
        float bv = b_n1[col];
        #pragma unroll
        for (int i = 0; i < 4; ++i)
            T[(quad*4+i)*TS + col] = f2bf(silu_f(acc[t][i] + bv));
    }
    __builtin_amdgcn_wave_barrier();

    short8 a2[4];
    #pragma unroll
    for (int kc = 0; kc < 4; ++kc)
        a2[kc] = *(const short8*)(&T[l15*TS + kc*32 + quad*8]);
    #pragma unroll
    for (int t = 0; t < 8; ++t) acc[t] = (floatx4){0,0,0,0};
    #pragma unroll
    for (int kc = 0; kc < 4; ++kc) {
        #pragma unroll
        for (int t = 0; t < 8; ++t) {
            short8 b = *(const short8*)(WT_n2 + (size_t)(t*16+l15)*HID + kc*32 + quad*8);
            acc[t] = __builtin_amdgcn_mfma_f32_16x16x32_bf16(a2[kc], b, acc[t], 0, 0, 0);
        }
    }
    #pragma unroll
    for (int t = 0; t < 8; ++t) {
        int col = t*16 + l15;
        float bv = b_n2[col];
        #pragma unroll
        for (int i = 0; i < 4; ++i) {
            int n = n0 + quad*4 + i;
            h_out[(size_t)n*HID + col] = h[(size_t)n*HID + col] + acc[t][i] + bv;
        }
    }
}

extern "C" void kernel_launch(void* const* d_in, const int* in_sizes, int n_in,
                              void* d_out, int out_size, void* d_ws, size_t ws_size,
                              hipStream_t stream) {
    const float* h          = (const float*)d_in[0];
    const float* x          = (const float*)d_in[1];
    const float* edge_attr  = (const float*)d_in[2];
    const int*   edge_index = (const int*)  d_in[3];
    const int*   mask       = (const int*)  d_in[4];
    const float* W_e1 = (const float*)d_in[5];
    const float* b_e1 = (const float*)d_in[6];
    const float* W_e2 = (const float*)d_in[7];
    const float* b_e2 = (const float*)d_in[8];
    const float* W_g  = (const float*)d_in[9];
    const float* b_g  = (const float*)d_in[10];
    const float* W_n1 = (const float*)d_in[11];
    const float* b_n1 = (const float*)d_in[12];
    const float* W_n2 = (const float*)d_in[13];
    const float* b_n2 = (const float*)d_in[14];
    const float* W_x1 = (const float*)d_in[15];
    const float* b_x1 = (const float*)d_in[16];
    const float* W_x2 = (const float*)d_in[17];

    char* ws = (char*)d_ws;
    float* agg = (float*)ws;                       ws += (size_t)NN*HID*4;
    float* dxv = (float*)ws;                       ws += (size_t)NN*3*4;
    int*   counts = (int*)ws;                      ws += (size_t)NN*4;
    int*   cursor = (int*)ws;                      ws += (size_t)NN*4;
    int*   order  = (int*)ws;                      ws += (size_t)NE*4;
    unsigned short* PD    = (unsigned short*)ws;   ws += (size_t)NN*HID*2;
    unsigned short* PS    = (unsigned short*)ws;   ws += (size_t)NN*HID*2;
    unsigned short* WT1d  = (unsigned short*)ws;   ws += (size_t)HID*HID*2;
    unsigned short* WT1s  = (unsigned short*)ws;   ws += (size_t)HID*HID*2;
    unsigned short* WT1r  = (unsigned short*)ws;   ws += (size_t)HID*32*2;
    unsigned short* WT_e2 = (unsigned short*)ws;   ws += (size_t)HID*HID*2;
    unsigned short* WT_x1 = (unsigned short*)ws;   ws += (size_t)HID*HID*2;
    unsigned short* WT_n1 = (unsigned short*)ws;   ws += (size_t)HID*KN1*2;
    unsigned short* WT_n2 = (unsigned short*)ws;   ws += (size_t)HID*HID*2;

    hipMemsetAsync(agg, 0, ((size_t)NN*HID + (size_t)NN*3)*sizeof(float), stream);
    hipMemsetAsync(counts, 0, (size_t)NN*sizeof(int), stream);

    prep_w_kernel<<<128, 320, 0, stream>>>(W_e1, W_e2, W_x1, W_n1, W_n2,
                                           WT1d, WT1s, WT1r, WT_e2, WT_x1, WT_n1, WT_n2);
    pd_kernel<<<NN/16, 64, 0, stream>>>(h, b_e1, WT1d, WT1s, PD, PS);
    hist_kernel<<<NE/256, 256, 0, stream>>>(edge_index, counts);
    scan_kernel<<<1, 1024, 0, stream>>>(counts, cursor);
    scatter_kernel<<<NE/256, 256, 0, stream>>>(edge_index, cursor, order);

    egnn_edge_mfma<<<NE/64, 256, 0, stream>>>(
        x, edge_attr, edge_index, order, PD, PS, WT1r, WT_e2, WT_x1,
        b_e2, W_g, b_g, b_x1, W_x2, agg, dxv);

    float* h_out = (float*)d_out;
    float* x_out = h_out + (size_t)NN*HID;

    egnn_node_mfma<<<NN/16, 64, 0, stream>>>(
        h, x, mask, agg, dxv, WT_n1, b_n1, WT_n2, b_n2, h_out, x_out);
}

// Round 9
// 523.988 us; speedup vs baseline: 1.8969x; 1.1393x over previous
//
#include <hip/hip_runtime.h>
#include <math.h>

#define HID 128
#define NUM_G 20
#define EF 4
#define NN 20000
#define NE 640000
#define KN1 256           // node GEMM1 K
#define TS 136            // LDS stride (bf16): 272B rows -> 2-way conflict only (free)

typedef __attribute__((ext_vector_type(8))) short short8;
typedef __attribute__((ext_vector_type(4))) short short4v;
typedef __attribute__((ext_vector_type(4))) float floatx4;

__device__ __forceinline__ float silu_f(float v){
    return v * __builtin_amdgcn_rcpf(1.0f + __expf(-v));
}
__device__ __forceinline__ float sigm_f(float v){
    return __builtin_amdgcn_rcpf(1.0f + __expf(-v));
}
__device__ __forceinline__ float tanh_f(float v){
    return 1.0f - 2.0f * __builtin_amdgcn_rcpf(1.0f + __expf(2.0f * v));
}
__device__ __forceinline__ unsigned short f2bf(float v){
    unsigned int u = __float_as_uint(v);
    u = (u + 0x7fffu + ((u >> 16) & 1u)) >> 16;
    return (unsigned short)u;
}
__device__ __forceinline__ float bf2f(unsigned short u){
    return __uint_as_float(((unsigned int)u) << 16);
}

// transpose + bf16-ify weights.
__global__ __launch_bounds__(320) void prep_w_kernel(
    const float* __restrict__ W_e1, const float* __restrict__ W_e2,
    const float* __restrict__ W_x1, const float* __restrict__ W_n1,
    const float* __restrict__ W_n2,
    unsigned short* __restrict__ WT1d, unsigned short* __restrict__ WT1s,
    unsigned short* __restrict__ WT1r,
    unsigned short* __restrict__ WT_e2, unsigned short* __restrict__ WT_x1,
    unsigned short* __restrict__ WT_n1, unsigned short* __restrict__ WT_n2)
{
    int n = blockIdx.x;   // output channel c
    int t = threadIdx.x;  // k index
    if (t < HID) {
        WT1d[n*HID + t] = f2bf(W_e1[t*HID + n]);
        WT1s[n*HID + t] = f2bf(W_e1[(HID+t)*HID + n]);
        WT_e2[n*HID + t] = f2bf(W_e2[t*HID + n]);
        WT_x1[n*HID + t] = f2bf(W_x1[t*HID + n]);
        WT_n2[n*HID + t] = f2bf(W_n2[t*HID + n]);
    }
    if (t < 32) WT1r[n*32 + t] = (t < NUM_G+EF) ? f2bf(W_e1[(256+t)*HID + n]) : (unsigned short)0;
    if (t < KN1) WT_n1[n*KN1 + t] = f2bf(W_n1[t*HID + n]);
}

// ---- counting sort of edges by dst ----
__global__ __launch_bounds__(256) void hist_kernel(
    const int* __restrict__ edge_index, int* __restrict__ counts)
{
    int e = blockIdx.x * 256 + threadIdx.x;
    atomicAdd(&counts[edge_index[NE + e]], 1);
}

__global__ __launch_bounds__(1024) void scan_kernel(
    const int* __restrict__ counts, int* __restrict__ cursor)
{
    __shared__ int part[1024];
    const int t = threadIdx.x;
    const int CH = (NN + 1023) / 1024;   // 20
    int base = t * CH;
    int s = 0;
    for (int i = 0; i < CH; ++i) { int idx = base + i; if (idx < NN) s += counts[idx]; }
    part[t] = s; __syncthreads();
    for (int off = 1; off < 1024; off <<= 1) {
        int v = (t >= off) ? part[t - off] : 0;
        __syncthreads();
        part[t] += v;
        __syncthreads();
    }
    int run = (t == 0) ? 0 : part[t - 1];
    for (int i = 0; i < CH; ++i) {
        int idx = base + i;
        if (idx < NN) { cursor[idx] = run; run += counts[idx]; }
    }
}

__global__ __launch_bounds__(256) void scatter_kernel(
    const int* __restrict__ edge_index, int* __restrict__ cursor,
    int* __restrict__ order)
{
    int e = blockIdx.x * 256 + threadIdx.x;
    int d = edge_index[NE + e];
    int pos = atomicAdd(&cursor[d], 1);
    order[pos] = e;
}

// ---- PD/PS precompute: PD[n] = h[n]@W1d + b_e1, PS[n] = h[n]@W1s (bf16 out) ----
__global__ __launch_bounds__(64, 4) void pd_kernel(
    const float* __restrict__ h, const float* __restrict__ b_e1,
    const unsigned short* __restrict__ WT1d, const unsigned short* __restrict__ WT1s,
    unsigned short* __restrict__ PD, unsigned short* __restrict__ PS)
{
    __shared__ __align__(16) unsigned short T[16*TS];

    const int lane = threadIdx.x;
    const int quad = lane >> 4;
    const int l15  = lane & 15;
    const int n0   = blockIdx.x * 16;
    const int node = n0 + l15;

    short8 ah[4];
    #pragma unroll
    for (int kc = 0; kc < 4; ++kc) {
        const float* p = h + (size_t)node*HID + kc*32 + quad*8;
        float4 f0 = *(const float4*)(p);
        float4 f1 = *(const float4*)(p + 4);
        short8 v;
        v[0]=(short)f2bf(f0.x); v[1]=(short)f2bf(f0.y); v[2]=(short)f2bf(f0.z); v[3]=(short)f2bf(f0.w);
        v[4]=(short)f2bf(f1.x); v[5]=(short)f2bf(f1.y); v[6]=(short)f2bf(f1.z); v[7]=(short)f2bf(f1.w);
        ah[kc] = v;
    }

    floatx4 ad[8], as[8];
    #pragma unroll
    for (int t = 0; t < 8; ++t) { ad[t] = (floatx4){0,0,0,0}; as[t] = (floatx4){0,0,0,0}; }
    #pragma unroll
    for (int kc = 0; kc < 4; ++kc) {
        #pragma unroll
        for (int t = 0; t < 8; ++t) {
            short8 bd = *(const short8*)(WT1d + (size_t)(t*16+l15)*HID + kc*32 + quad*8);
            short8 bs = *(const short8*)(WT1s + (size_t)(t*16+l15)*HID + kc*32 + quad*8);
            ad[t] = __builtin_amdgcn_mfma_f32_16x16x32_bf16(ah[kc], bd, ad[t], 0, 0, 0);
            as[t] = __builtin_amdgcn_mfma_f32_16x16x32_bf16(ah[kc], bs, as[t], 0, 0, 0);
        }
    }
    #pragma unroll
    for (int t = 0; t < 8; ++t) {
        int col = t*16 + l15;
        float bv = b_e1[col];
        #pragma unroll
        for (int i = 0; i < 4; ++i)
            T[(quad*4+i)*TS + col] = f2bf(ad[t][i] + bv);
    }
    __builtin_amdgcn_wave_barrier();
    #pragma unroll
    for (int kc = 0; kc < 4; ++kc)
        *(short8*)(PD + (size_t)node*HID + kc*32 + quad*8) =
            *(const short8*)(&T[l15*TS + kc*32 + quad*8]);
    __builtin_amdgcn_wave_barrier();
    #pragma unroll
    for (int t = 0; t < 8; ++t) {
        int col = t*16 + l15;
        #pragma unroll
        for (int i = 0; i < 4; ++i)
            T[(quad*4+i)*TS + col] = f2bf(as[t][i]);
    }
    __builtin_amdgcn_wave_barrier();
    #pragma unroll
    for (int kc = 0; kc < 4; ++kc)
        *(short8*)(PS + (size_t)node*HID + kc*32 + quad*8) =
            *(const short8*)(&T[l15*TS + kc*32 + quad*8]);
}

// ---- edge kernel: 4 autonomous waves/block, 32 sorted edges/wave (two 16-row tiles
// share every B fragment), GEMM1 replaced by PD/PS gather + rbf MFMA ----
__global__ __launch_bounds__(256, 3) void egnn_edge_mfma(
    const float* __restrict__ x, const float* __restrict__ edge_attr,
    const int* __restrict__ edge_index, const int* __restrict__ order,
    const unsigned short* __restrict__ PD, const unsigned short* __restrict__ PS,
    const unsigned short* __restrict__ WT1r,
    const unsigned short* __restrict__ WT_e2,
    const unsigned short* __restrict__ WT_x1,
    const float* __restrict__ b_e2,
    const float* __restrict__ W_g,  const float* __restrict__ b_g,
    const float* __restrict__ b_x1, const float* __restrict__ W_x2,
    float* __restrict__ agg, float* __restrict__ dxv)
{
    __shared__ __align__(16) unsigned short T[4][32*TS];   // rbf-acc, then m2
    __shared__ int   s_dst[4][33];
    __shared__ float s_g[4][32];
    __shared__ float s_vec[4][96];

    const int wv   = threadIdx.x >> 6;
    const int lane = threadIdx.x & 63;
    const int quad = lane >> 4;
    const int l15  = lane & 15;
    const int e0   = (blockIdx.x * 4 + wv) * 32;

    unsigned short* Tw = &T[wv][0];

    // --- meta in registers (lanes 0..31 own one edge each) ---
    int   ereg = 0, sreg = 0, dreg = 0;
    float rxr = 0.f, ryr = 0.f, rzr = 0.f, rreg = 0.f;
    if (lane < 32) {
        ereg = order[e0 + lane];
        sreg = edge_index[ereg];
        dreg = edge_index[NE + ereg];
        rxr = x[dreg*3+0] - x[sreg*3+0];
        ryr = x[dreg*3+1] - x[sreg*3+1];
        rzr = x[dreg*3+2] - x[sreg*3+2];
        rreg = sqrtf(rxr*rxr + ryr*ryr + rzr*rzr + 1e-8f);
        s_dst[wv][lane] = dreg;
    }
    if (lane == 32) s_dst[wv][32] = -1;

    const int   nd0  = __shfl(dreg, l15);
    const int   ns0  = __shfl(sreg, l15);
    const int   eid0 = __shfl(ereg, l15);
    const float rr0  = __shfl(rreg, l15);
    const int   nd1  = __shfl(dreg, 16 + l15);
    const int   ns1  = __shfl(sreg, 16 + l15);
    const int   eid1 = __shfl(ereg, 16 + l15);
    const float rr1  = __shfl(rreg, 16 + l15);

    // --- issue long-latency PD/PS gathers first; rbf VALU overlaps them ---
    short8 pdv0[4], psv0[4], pdv1[4], psv1[4];
    #pragma unroll
    for (int kc = 0; kc < 4; ++kc) {
        pdv0[kc] = *(const short8*)(PD + (size_t)nd0*HID + kc*32 + quad*8);
        psv0[kc] = *(const short8*)(PS + (size_t)ns0*HID + kc*32 + quad*8);
        pdv1[kc] = *(const short8*)(PD + (size_t)nd1*HID + kc*32 + quad*8);
        psv1[kc] = *(const short8*)(PS + (size_t)ns1*HID + kc*32 + quad*8);
    }

    // rbf fragments for both tiles
    short8 ar0, ar1;
    {
        const float step  = 10.0f / 19.0f;
        const float coeff = -0.5f / (step*step);
        #pragma unroll
        for (int j = 0; j < 8; ++j) {
            int col = quad*8 + j;
            float v0 = 0.f, v1 = 0.f;
            if (col < NUM_G) {
                float d0 = rr0 - step*(float)col;
                float d1 = rr1 - step*(float)col;
                v0 = __expf(coeff*d0*d0);
                v1 = __expf(coeff*d1*d1);
            } else if (col < NUM_G+EF) {
                v0 = edge_attr[(size_t)eid0*EF + (col-NUM_G)];
                v1 = edge_attr[(size_t)eid1*EF + (col-NUM_G)];
            }
            ar0[j] = (short)f2bf(v0);
            ar1[j] = (short)f2bf(v1);
        }
    }

    floatx4 acc0[8], acc1[8];
    #pragma unroll
    for (int t = 0; t < 8; ++t) { acc0[t] = (floatx4){0,0,0,0}; acc1[t] = (floatx4){0,0,0,0}; }
    #pragma unroll
    for (int t = 0; t < 8; ++t) {
        short8 b = *(const short8*)(WT1r + (size_t)(t*16+l15)*32 + quad*8);
        acc0[t] = __builtin_amdgcn_mfma_f32_16x16x32_bf16(ar0, b, acc0[t], 0, 0, 0);
        acc1[t] = __builtin_amdgcn_mfma_f32_16x16x32_bf16(ar1, b, acc1[t], 0, 0, 0);
    }
    // raw rbf contribution -> T rows 0..15 (tile0), 16..31 (tile1)
    #pragma unroll
    for (int t = 0; t < 8; ++t) {
        int col = t*16 + l15;
        #pragma unroll
        for (int i = 0; i < 4; ++i) {
            Tw[(quad*4+i)*TS + col]    = f2bf(acc0[t][i]);
            Tw[(16+quad*4+i)*TS + col] = f2bf(acc1[t][i]);
        }
    }
    __builtin_amdgcn_wave_barrier();

    // layer-1 finalize: m1 = silu(PD[dst]+PS[src]+rbf)  (bias folded in PD)
    short8 a2[8];
    #pragma unroll
    for (int kc = 0; kc < 4; ++kc) {
        short8 rv0 = *(const short8*)(&Tw[l15*TS + kc*32 + quad*8]);
        short8 rv1 = *(const short8*)(&Tw[(16+l15)*TS + kc*32 + quad*8]);
        short8 o0, o1;
        #pragma unroll
        for (int j = 0; j < 8; ++j) {
            float v0 = bf2f((unsigned short)pdv0[kc][j])
                     + bf2f((unsigned short)psv0[kc][j])
                     + bf2f((unsigned short)rv0[j]);
            float v1 = bf2f((unsigned short)pdv1[kc][j])
                     + bf2f((unsigned short)psv1[kc][j])
                     + bf2f((unsigned short)rv1[j]);
            o0[j] = (short)f2bf(silu_f(v0));
            o1[j] = (short)f2bf(silu_f(v1));
        }
        a2[kc]   = o0;
        a2[4+kc] = o1;
    }
    __builtin_amdgcn_wave_barrier();

    // --- GEMM2: m2 = silu(m1 @ W_e2 + b), gate; B loaded once for both tiles ---
    #pragma unroll
    for (int t = 0; t < 8; ++t) { acc0[t] = (floatx4){0,0,0,0}; acc1[t] = (floatx4){0,0,0,0}; }
    #pragma unroll
    for (int kc = 0; kc < 4; ++kc) {
        #pragma unroll
        for (int t = 0; t < 8; ++t) {
            short8 b = *(const short8*)(WT_e2 + (size_t)(t*16+l15)*HID + kc*32 + quad*8);
            acc0[t] = __builtin_amdgcn_mfma_f32_16x16x32_bf16(a2[kc],   b, acc0[t], 0, 0, 0);
            acc1[t] = __builtin_amdgcn_mfma_f32_16x16x32_bf16(a2[4+kc], b, acc1[t], 0, 0, 0);
        }
    }
    {
        float gp0[4] = {0,0,0,0}, gp1[4] = {0,0,0,0};
        #pragma unroll
        for (int t = 0; t < 8; ++t) {
            int col = t*16 + l15;
            float bv = b_e2[col];
            float wgv = W_g[col];
            #pragma unroll
            for (int i = 0; i < 4; ++i) {
                float m20 = silu_f(acc0[t][i] + bv);
                float m21 = silu_f(acc1[t][i] + bv);
                gp0[i] += m20 * wgv;
                gp1[i] += m21 * wgv;
                Tw[(quad*4+i)*TS + col]    = f2bf(m20);
                Tw[(16+quad*4+i)*TS + col] = f2bf(m21);
            }
        }
        const float bg0 = b_g[0];
        #pragma unroll
        for (int i = 0; i < 4; ++i) {
            gp0[i] += __shfl_xor(gp0[i], 1); gp0[i] += __shfl_xor(gp0[i], 2);
            gp0[i] += __shfl_xor(gp0[i], 4); gp0[i] += __shfl_xor(gp0[i], 8);
            gp1[i] += __shfl_xor(gp1[i], 1); gp1[i] += __shfl_xor(gp1[i], 2);
            gp1[i] += __shfl_xor(gp1[i], 4); gp1[i] += __shfl_xor(gp1[i], 8);
        }
        if (l15 == 0) {
            #pragma unroll
            for (int i = 0; i < 4; ++i) {
                s_g[wv][quad*4 + i]      = sigm_f(gp0[i] + bg0);
                s_g[wv][16 + quad*4 + i] = sigm_f(gp1[i] + bg0);
            }
        }
    }
    __builtin_amdgcn_wave_barrier();

    // --- GEMM3: coord head (m2 from T, both tiles) ---
    #pragma unroll
    for (int kc = 0; kc < 4; ++kc) {
        a2[kc]   = *(const short8*)(&Tw[l15*TS + kc*32 + quad*8]);
        a2[4+kc] = *(const short8*)(&Tw[(16+l15)*TS + kc*32 + quad*8]);
    }
    #pragma unroll
    for (int t = 0; t < 8; ++t) { acc0[t] = (floatx4){0,0,0,0}; acc1[t] = (floatx4){0,0,0,0}; }
    #pragma unroll
    for (int kc = 0; kc < 4; ++kc) {
        #pragma unroll
        for (int t = 0; t < 8; ++t) {
            short8 b = *(const short8*)(WT_x1 + (size_t)(t*16+l15)*HID + kc*32 + quad*8);
            acc0[t] = __builtin_amdgcn_mfma_f32_16x16x32_bf16(a2[kc],   b, acc0[t], 0, 0, 0);
            acc1[t] = __builtin_amdgcn_mfma_f32_16x16x32_bf16(a2[4+kc], b, acc1[t], 0, 0, 0);
        }
    }
    {
        float cp0[4] = {0,0,0,0}, cp1[4] = {0,0,0,0};
        #pragma unroll
        for (int t = 0; t < 8; ++t) {
            int col = t*16 + l15;
            float bv = b_x1[col];
            float wx = W_x2[col];
            #pragma unroll
            for (int i = 0; i < 4; ++i) {
                cp0[i] += silu_f(acc0[t][i] + bv) * wx;
                cp1[i] += silu_f(acc1[t][i] + bv) * wx;
            }
        }
        #pragma unroll
        for (int i = 0; i < 4; ++i) {
            cp0[i] += __shfl_xor(cp0[i], 1); cp0[i] += __shfl_xor(cp0[i], 2);
            cp0[i] += __shfl_xor(cp0[i], 4); cp0[i] += __shfl_xor(cp0[i], 8);
            cp1[i] += __shfl_xor(cp1[i], 1); cp1[i] += __shfl_xor(cp1[i], 2);
            cp1[i] += __shfl_xor(cp1[i], 4); cp1[i] += __shfl_xor(cp1[i], 8);
        }
        if (l15 < 3) {
            #pragma unroll
            for (int i = 0; i < 4; ++i) {
                int r0 = quad*4 + i;
                int r1 = 16 + quad*4 + i;
                float relc0 = (l15 == 0) ? __shfl(rxr, r0) : ((l15 == 1) ? __shfl(ryr, r0) : __shfl(rzr, r0));
                float relc1 = (l15 == 0) ? __shfl(rxr, r1) : ((l15 == 1) ? __shfl(ryr, r1) : __shfl(rzr, r1));
                float rv0 = __shfl(rreg, r0);
                float rv1 = __shfl(rreg, r1);
                s_vec[wv][r0*3 + l15] = relc0 * __builtin_amdgcn_rcpf(rv0 + 1.0f) * tanh_f(cp0[i]);
                s_vec[wv][r1*3 + l15] = relc1 * __builtin_amdgcn_rcpf(rv1 + 1.0f) * tanh_f(cp1[i]);
            }
        }
    }
    __builtin_amdgcn_wave_barrier();

    // --- scatters last ---
    {
        float am0 = 0.f, am1 = 0.f;
        #pragma unroll
        for (int r = 0; r < 32; ++r) {
            unsigned int pv = *(const unsigned int*)(&Tw[r*TS + lane*2]);
            float gr = s_g[wv][r];
            am0 += bf2f((unsigned short)(pv & 0xffffu)) * gr;
            am1 += bf2f((unsigned short)(pv >> 16)) * gr;
            int dr = s_dst[wv][r];
            if (dr != s_dst[wv][r+1]) {
                atomicAdd(&agg[(size_t)dr*HID + lane*2],     am0);
                atomicAdd(&agg[(size_t)dr*HID + lane*2 + 1], am1);
                am0 = 0.f; am1 = 0.f;
            }
        }
    }
    if (lane < 3) {
        float a = 0.f;
        #pragma unroll
        for (int r = 0; r < 32; ++r) {
            a += s_vec[wv][r*3 + lane];
            int dr = s_dst[wv][r];
            if (dr != s_dst[wv][r+1]) {
                atomicAdd(&dxv[(size_t)dr*3 + lane], a);
                a = 0.f;
            }
        }
    }
}

// ---- node kernel: ONE WAVE per block, 16 nodes ----
__global__ __launch_bounds__(64, 4) void egnn_node_mfma(
    const float* __restrict__ h, const float* __restrict__ x,
    const int* __restrict__ mask,
    const float* __restrict__ agg, const float* __restrict__ dxv,
    const unsigned short* __restrict__ WT_n1, const float* __restrict__ b_n1,
    const unsigned short* __restrict__ WT_n2, const float* __restrict__ b_n2,
    float* __restrict__ h_out, float* __restrict__ x_out)
{
    __shared__ __align__(16) unsigned short T[16*TS];

    const int lane = threadIdx.x;
    const int quad = lane >> 4;
    const int l15  = lane & 15;
    const int n0   = blockIdx.x * 16;

    if (lane < 48) {
        int r = lane / 3, c = lane % 3;
        int n = n0 + r;
        x_out[n*3 + c] = x[n*3 + c] + dxv[n*3 + c] * (float)mask[n];
    }

    const int node = n0 + l15;
    short8 a1[8];
    #pragma unroll
    for (int kc = 0; kc < 4; ++kc) {
        const float* p = agg + (size_t)node*HID + kc*32 + quad*8;
        float4 f0 = *(const float4*)(p);
        float4 f1 = *(const float4*)(p + 4);
        short8 v;
        v[0]=(short)f2bf(f0.x); v[1]=(short)f2bf(f0.y); v[2]=(short)f2bf(f0.z); v[3]=(short)f2bf(f0.w);
        v[4]=(short)f2bf(f1.x); v[5]=(short)f2bf(f1.y); v[6]=(short)f2bf(f1.z); v[7]=(short)f2bf(f1.w);
        a1[kc] = v;
    }
    #pragma unroll
    for (int kc = 0; kc < 4; ++kc) {
        const float* p = h + (size_t)node*HID + kc*32 + quad*8;
        float4 f0 = *(const float4*)(p);
        float4 f1 = *(const float4*)(p + 4);
        short8 v;
        v[0]=(short)f2bf(f0.x); v[1]=(short)f2bf(f0.y); v[2]=(short)f2bf(f0.z); v[3]=(short)f2bf(f0.w);
        v[4]=(short)f2bf(f1.x); v[5]=(short)f2bf(f1.y); v[6]=(short)f2bf(f1.z); v[7]=(short)f2bf(f1.w);
        a1[4+kc] = v;
    }

    floatx4 acc[8];
    #pragma unroll
    for (int t = 0; t < 8; ++t) acc[t] = (floatx4){0,0,0,0};
    #pragma unroll
    for (int kc = 0; kc < 8; ++kc) {
        #pragma unroll
        for (int t = 0; t < 8; ++t) {
            short8 b = *(const short8*)(WT_n1 + (size_t)(t*16+l15)*KN1 + kc*32 + quad*8);
            acc[t] = __builtin_amdgcn_mfma_f32_16x16x32_bf16(a1[kc], b, acc[t], 0, 0, 0);
        }
    }
    #pragma unroll
    for (int t = 0; t < 8; ++t) {
        int col = t*16 + l15;
        float bv = b_n1[col];
        #pragma unroll
        for (int i = 0; i < 4; ++i)
            T[(quad*4+i)*TS + col] = f2bf(silu_f(acc[t][i] + bv));
    }
    __builtin_amdgcn_wave_barrier();

    short8 a2[4];
    #pragma unroll
    for (int kc = 0; kc < 4; ++kc)
        a2[kc] = *(const short8*)(&T[l15*TS + kc*32 + quad*8]);
    #pragma unroll
    for (int t = 0; t < 8; ++t) acc[t] = (floatx4){0,0,0,0};
    #pragma unroll
    for (int kc = 0; kc < 4; ++kc) {
        #pragma unroll
        for (int t = 0; t < 8; ++t) {
            short8 b = *(const short8*)(WT_n2 + (size_t)(t*16+l15)*HID + kc*32 + quad*8);
            acc[t] = __builtin_amdgcn_mfma_f32_16x16x32_bf16(a2[kc], b, acc[t], 0, 0, 0);
        }
    }
    #pragma unroll
    for (int t = 0; t < 8; ++t) {
        int col = t*16 + l15;
        float bv = b_n2[col];
        #pragma unroll
        for (int i = 0; i < 4; ++i) {
            int n = n0 + quad*4 + i;
            h_out[(size_t)n*HID + col] = h[(size_t)n*HID + col] + acc[t][i] + bv;
        }
    }
}

extern "C" void kernel_launch(void* const* d_in, const int* in_sizes, int n_in,
                              void* d_out, int out_size, void* d_ws, size_t ws_size,
                              hipStream_t stream) {
    const float* h          = (const float*)d_in[0];
    const float* x          = (const float*)d_in[1];
    const float* edge_attr  = (const float*)d_in[2];
    const int*   edge_index = (const int*)  d_in[3];
    const int*   mask       = (const int*)  d_in[4];
    const float* W_e1 = (const float*)d_in[5];
    const float* b_e1 = (const float*)d_in[6];
    const float* W_e2 = (const float*)d_in[7];
    const float* b_e2 = (const float*)d_in[8];
    const float* W_g  = (const float*)d_in[9];
    const float* b_g  = (const float*)d_in[10];
    const float* W_n1 = (const float*)d_in[11];
    const float* b_n1 = (const float*)d_in[12];
    const float* W_n2 = (const float*)d_in[13];
    const float* b_n2 = (const float*)d_in[14];
    const float* W_x1 = (const float*)d_in[15];
    const float* b_x1 = (const float*)d_in[16];
    const float* W_x2 = (const float*)d_in[17];

    char* ws = (char*)d_ws;
    float* agg = (float*)ws;                       ws += (size_t)NN*HID*4;
    float* dxv = (float*)ws;                       ws += (size_t)NN*3*4;
    int*   counts = (int*)ws;                      ws += (size_t)NN*4;
    int*   cursor = (int*)ws;                      ws += (size_t)NN*4;
    int*   order  = (int*)ws;                      ws += (size_t)NE*4;
    unsigned short* PD    = (unsigned short*)ws;   ws += (size_t)NN*HID*2;
    unsigned short* PS    = (unsigned short*)ws;   ws += (size_t)NN*HID*2;
    unsigned short* WT1d  = (unsigned short*)ws;   ws += (size_t)HID*HID*2;
    unsigned short* WT1s  = (unsigned short*)ws;   ws += (size_t)HID*HID*2;
    unsigned short* WT1r  = (unsigned short*)ws;   ws += (size_t)HID*32*2;
    unsigned short* WT_e2 = (unsigned short*)ws;   ws += (size_t)HID*HID*2;
    unsigned short* WT_x1 = (unsigned short*)ws;   ws += (size_t)HID*HID*2;
    unsigned short* WT_n1 = (unsigned short*)ws;   ws += (size_t)HID*KN1*2;
    unsigned short* WT_n2 = (unsigned short*)ws;   ws += (size_t)HID*HID*2;

    hipMemsetAsync(agg, 0, ((size_t)NN*HID + (size_t)NN*3)*sizeof(float), stream);
    hipMemsetAsync(counts, 0, (size_t)NN*sizeof(int), stream);

    prep_w_kernel<<<128, 320, 0, stream>>>(W_e1, W_e2, W_x1, W_n1, W_n2,
                                           WT1d, WT1s, WT1r, WT_e2, WT_x1, WT_n1, WT_n2);
    pd_kernel<<<NN/16, 64, 0, stream>>>(h, b_e1, WT1d, WT1s, PD, PS);
    hist_kernel<<<NE/256, 256, 0, stream>>>(edge_index, counts);
    scan_kernel<<<1, 1024, 0, stream>>>(counts, cursor);
    scatter_kernel<<<NE/256, 256, 0, stream>>>(edge_index, cursor, order);

    egnn_edge_mfma<<<NE/128, 256, 0, stream>>>(
        x, edge_attr, edge_index, order, PD, PS, WT1r, WT_e2, WT_x1,
        b_e2, W_g, b_g, b_x1, W_x2, agg, dxv);

    float* h_out = (float*)d_out;
    float* x_out = h_out + (size_t)NN*HID;

    egnn_node_mfma<<<NN/16, 64, 0, stream>>>(
        h, x, mask, agg, dxv, WT_n1, b_n1, WT_n2, b_n2, h_out, x_out);
}